// Round 3
// baseline (67.413 us; speedup 1.0000x reference)
//
#include <hip/hip_runtime.h>

// Problem constants (from reference):
//   N=64, C=4, LPC=8, KPL=4, D=4096, BLOCK=C*LPC*KPL=128, P=3*BLOCK=384
// out[n,c,d] = sum_g amp[n,c,g] * exp(-0.5*(x[n,c,d]-mu[n,c,g])^2 / sigma[n,c,g]^2)
// g ranges over the LPC*KPL = 32 gaussians of channel c.
//
// Formulation:  exp2(-(x*r + mmr)^2),  r = sqrt(0.5*log2 e)/sigma,  mmr = -mu*r.
// Packed-fp32 (VOP3P) inner loop: arithmetic on float2 so the backend emits
// v_pk_fma_f32 / v_pk_mul_f32 (2 elements per instruction). Per-gaussian
// scalars are pre-splatted to float2 in LDS so a single ds_read_b64 broadcast
// feeds both halves (no per-gaussian v_mov splats).
// Per gaussian per wave: 6 packed VALU (12 cy) + 4 v_exp_f32 (32 cy) ~= 44 cy
// vs 56 cy for the scalar version.

#define NN   64
#define CC   4
#define GG   32        // LPC*KPL gaussians per (n,c)
#define DD   4096
#define PP   384       // network_outputs row length
#define TPB  256       // threads per block
#define EPT  4         // one float4 per thread
// Each block covers TPB*EPT = 1024 contiguous d's of one (n,c) row.
// Grid = (DD/1024, NN*CC) = (4, 256) = 1024 blocks -> 4 blocks/CU, 4 waves/SIMD.

typedef float v2f __attribute__((ext_vector_type(2)));

__global__ __launch_bounds__(TPB) void gauss_mix_kernel(
    const float* __restrict__ x,
    const float* __restrict__ net,        // (N, P)
    const int*   __restrict__ amp_idx,    // (C, LPC, KPL) flat = C*32
    const int*   __restrict__ mu_idx,
    const int*   __restrict__ sigma_idx,
    float* __restrict__ out)
{
    __shared__ v2f s_amp[GG];   // {a, a}
    __shared__ v2f s_r[GG];     // {r, r},  r = sqrt(0.5*log2e)/sigma
    __shared__ v2f s_mmr[GG];   // {-mu*r, -mu*r}

    const int row = blockIdx.y;          // n*C + c
    const int n   = row >> 2;            // / CC
    const int c   = row & (CC - 1);
    const int tid = threadIdx.x;

    if (tid < GG) {
        const int gi   = c * GG + tid;
        const int base = n * PP;
        const float a  = net[base + amp_idx[gi]];
        const float m  = net[base + mu_idx[gi]];
        const float s  = net[base + sigma_idx[gi]];
        const float r  = 0.84932178f / s;   // sqrt(0.5 * 1.4426950408889634)
        const float mmr = -m * r;
        s_amp[tid] = (v2f){a, a};
        s_r[tid]   = (v2f){r, r};
        s_mmr[tid] = (v2f){mmr, mmr};
    }
    __syncthreads();

    const int d0 = blockIdx.x * (TPB * EPT) + tid * EPT;
    const size_t off = (size_t)row * DD + d0;

    const float4 xv = *(const float4*)(x + off);
    const v2f x01 = (v2f){xv.x, xv.y};
    const v2f x23 = (v2f){xv.z, xv.w};
    v2f acc01 = (v2f){0.f, 0.f};
    v2f acc23 = (v2f){0.f, 0.f};

    #pragma unroll
    for (int g = 0; g < GG; ++g) {
        const v2f r   = s_r[g];     // ds_read_b64 broadcast (conflict-free)
        const v2f mmr = s_mmr[g];
        const v2f a   = s_amp[g];
        const v2f u01 = x01 * r + mmr;    // v_pk_fma_f32
        const v2f u23 = x23 * r + mmr;
        const v2f q01 = u01 * u01;        // v_pk_mul_f32
        const v2f q23 = u23 * u23;
        v2f e01, e23;                     // scalar v_exp_f32, neg input modifier
        e01.x = __builtin_amdgcn_exp2f(-q01.x);
        e01.y = __builtin_amdgcn_exp2f(-q01.y);
        e23.x = __builtin_amdgcn_exp2f(-q23.x);
        e23.y = __builtin_amdgcn_exp2f(-q23.y);
        acc01 = a * e01 + acc01;          // v_pk_fma_f32
        acc23 = a * e23 + acc23;
    }

    float4 o;
    o.x = acc01.x; o.y = acc01.y; o.z = acc23.x; o.w = acc23.y;
    *(float4*)(out + off) = o;
}

extern "C" void kernel_launch(void* const* d_in, const int* in_sizes, int n_in,
                              void* d_out, int out_size, void* d_ws, size_t ws_size,
                              hipStream_t stream)
{
    const float* x       = (const float*)d_in[0];   // (N, C, D)
    const float* net     = (const float*)d_in[1];   // (N, P)
    const int*   amp_idx = (const int*)d_in[2];     // (C, LPC, KPL)
    const int*   mu_idx  = (const int*)d_in[3];
    const int*   sig_idx = (const int*)d_in[4];
    float*       out     = (float*)d_out;           // (N, C, D)

    dim3 grid(DD / (TPB * EPT), NN * CC);
    dim3 block(TPB);
    gauss_mix_kernel<<<grid, block, 0, stream>>>(x, net, amp_idx, mu_idx, sig_idx, out);
}